// Round 5
// baseline (355.854 us; speedup 1.0000x reference)
//
#include <hip/hip_runtime.h>

#define N_NODES 65536
#define IN_FEAT 16
#define HIDDEN 32
#define NUM_EDGES 1048576
#define NUM_GRAPHS 16
#define NODES_PER_GRAPH 4096
#define FC1_IN (NODES_PER_GRAPH * HIDDEN) /* 131072 */
#define FC1_OUT 256
#define FC2_OUT 64
#define FC1_KCHUNK 128
#define FC1_BLOCKS (FC1_IN / FC1_KCHUNK) /* 1024 */
#define NB 256          /* buckets = dst>>8 */
#define BUCKET_CAP 5120 /* mean 4096, sd 64 -> 16 sigma headroom */
#define EPB_A 4096      /* edges per phase-A block */

// ---- init bucket cursors to fixed-capacity bases ----
__global__ void initcur_kernel(int* __restrict__ bucket_cursor) {
    bucket_cursor[threadIdx.x] = threadIdx.x * BUCKET_CAP;
}

// ---- phase A: bin edges by dst>>8 with chunk-contiguous writes ----
__global__ void binA_kernel(const int* __restrict__ src, const int* __restrict__ dst,
                            int* __restrict__ bucket_cursor, int* __restrict__ binned) {
    __shared__ int hist[NB];
    __shared__ int base[NB];
    __shared__ int cur[NB];
    int t = threadIdx.x;
    hist[t] = 0;
    __syncthreads();
    int e0 = blockIdx.x * EPB_A;
    int s[16], d[16];
#pragma unroll
    for (int i = 0; i < 16; i++) {
        int e = e0 + t + 256 * i;
        s[i] = src[e];
        d[i] = dst[e];
    }
#pragma unroll
    for (int i = 0; i < 16; i++) atomicAdd(&hist[d[i] >> 8], 1);
    __syncthreads();
    base[t] = atomicAdd(&bucket_cursor[t], hist[t]);
    cur[t] = 0;
    __syncthreads();
#pragma unroll
    for (int i = 0; i < 16; i++) {
        int b = d[i] >> 8;
        int r = atomicAdd(&cur[b], 1);
        binned[base[b] + r] = s[i] | ((d[i] & 255) << 16);
    }
}

// ---- phase B: per-bucket LDS counting sort by dst low byte ----
// emits csr_src, rowstart/rowend, dinv, and x~ = x * dinv (layer-1 prescale).
__global__ void sortB_kernel(const int* __restrict__ bucket_cursor, const int* __restrict__ binned,
                             int* __restrict__ csr_src, int* __restrict__ rowstart,
                             int* __restrict__ rowend, float* __restrict__ dinv,
                             const float* __restrict__ x, float* __restrict__ xs) {
    __shared__ int hist[NB];
    __shared__ int scanbuf[NB];
    __shared__ int start[NB];
    __shared__ int cur[NB];
    int t = threadIdx.x;
    int b = blockIdx.x;
    int bbase = b * BUCKET_CAP;
    int cnt = bucket_cursor[b] - bbase;
    hist[t] = 0;
    __syncthreads();
    for (int i = t; i < cnt; i += 256) atomicAdd(&hist[binned[bbase + i] >> 16], 1);
    __syncthreads();
    int v = hist[t];
    scanbuf[t] = v;
    __syncthreads();
    for (int off = 1; off < 256; off <<= 1) {
        int y = (t >= off) ? scanbuf[t - off] : 0;
        __syncthreads();
        scanbuf[t] += y;
        __syncthreads();
    }
    int excl = scanbuf[t] - v;  // exclusive prefix within bucket
    start[t] = excl;
    cur[t] = 0;
    __syncthreads();
    for (int i = t; i < cnt; i += 256) {
        int p = binned[bbase + i];
        int dl = p >> 16;
        int r = atomicAdd(&cur[dl], 1);
        csr_src[bbase + start[dl] + r] = p & 0xFFFF;
    }
    int n = b * 256 + t;
    rowstart[n] = bbase + excl;
    rowend[n] = bbase + excl + v;
    float di = rsqrtf((float)v + 1.0f);
    dinv[n] = di;
    const float4* x4 = (const float4*)x;
    float4* xs4 = (float4*)xs;
#pragma unroll
    for (int q = 0; q < IN_FEAT / 4; q++) {
        float4 xv = x4[(size_t)n * (IN_FEAT / 4) + q];
        xv.x *= di; xv.y *= di; xv.z *= di; xv.w *= di;
        xs4[(size_t)n * (IN_FEAT / 4) + q] = xv;
    }
}

// ---- gather: acc[n] = dinv[n]*(sum_{s in N(n)} h~[s] + h~[n]); F4 float4/row ----
// EPI: apply +bias, relu (conv output); else raw scaled sum (layer-1 pre-agg).
// 8-deep MLP: 8 independent 16B row-gathers in flight per node-group.
template <int F4, int LOG2F4, bool EPI>
__global__ void gather_kernel(const int* __restrict__ rowstart, const int* __restrict__ rowend,
                              const int* __restrict__ csr_src, const float* __restrict__ h,
                              const float* __restrict__ dinv, const float* __restrict__ b,
                              float* __restrict__ out) {
    int t = blockIdx.x * 256 + threadIdx.x;
    int f4 = t & (F4 - 1);
    int n = t >> LOG2F4;
    const float4* h4 = (const float4*)h;
    float4 acc = h4[(size_t)n * F4 + f4];  // self-loop term
    int beg = rowstart[n];
    int end = rowend[n];
    int i = beg;
    for (; i + 8 <= end; i += 8) {
        int s[8];
#pragma unroll
        for (int u = 0; u < 8; u++) s[u] = csr_src[i + u];
        float4 a[8];
#pragma unroll
        for (int u = 0; u < 8; u++) a[u] = h4[(size_t)s[u] * F4 + f4];
#pragma unroll
        for (int u = 0; u < 8; u++) {
            acc.x += a[u].x; acc.y += a[u].y; acc.z += a[u].z; acc.w += a[u].w;
        }
    }
    if (i + 4 <= end) {
        int s[4];
#pragma unroll
        for (int u = 0; u < 4; u++) s[u] = csr_src[i + u];
        float4 a[4];
#pragma unroll
        for (int u = 0; u < 4; u++) a[u] = h4[(size_t)s[u] * F4 + f4];
#pragma unroll
        for (int u = 0; u < 4; u++) {
            acc.x += a[u].x; acc.y += a[u].y; acc.z += a[u].z; acc.w += a[u].w;
        }
        i += 4;
    }
    for (; i < end; i++) {
        float4 a = h4[(size_t)csr_src[i] * F4 + f4];
        acc.x += a.x; acc.y += a.y; acc.z += a.z; acc.w += a.w;
    }
    float di = dinv[n];
    float4 v;
    v.x = acc.x * di; v.y = acc.y * di; v.z = acc.z * di; v.w = acc.w * di;
    if (EPI) {
        float4 bb = ((const float4*)b)[f4];
        v.x += bb.x; v.y += bb.y; v.z += bb.z; v.w += bb.w;
        v.x = v.x > 0.f ? v.x : 0.f;
        v.y = v.y > 0.f ? v.y : 0.f;
        v.z = v.z > 0.f ? v.z : 0.f;
        v.w = v.w > 0.f ? v.w : 0.f;
    }
    ((float4*)out)[(size_t)n * F4 + f4] = v;
}

// ---- h = (in @ W) [epilogue: *dinv  OR  +bias,relu]; 32 nodes x 8 f4-cols ----
template <int FIN, bool BIAS_RELU>
__global__ void matmul_kernel(const float* __restrict__ in, const float* __restrict__ W,
                              const float* __restrict__ scale_or_bias, float* __restrict__ h) {
    __shared__ float4 Ws4[FIN * 8];           // W[FIN][32] as float4
    __shared__ float rows[32 * (FIN + 1)];    // +1 pad: conflict-free nl stride
    int t = threadIdx.x;
    for (int i = t; i < FIN * 8; i += 256) Ws4[i] = ((const float4*)W)[i];
    size_t base = (size_t)blockIdx.x * 32 * FIN;
    for (int i = t; i < 32 * FIN; i += 256) {
        int nn = i / FIN;
        int ff = i & (FIN - 1);
        rows[nn * (FIN + 1) + ff] = in[base + i];
    }
    __syncthreads();
    int fo4 = t & 7;
    int nl = t >> 3;
    int n = blockIdx.x * 32 + nl;
    float4 acc = make_float4(0.f, 0.f, 0.f, 0.f);
#pragma unroll
    for (int fi = 0; fi < FIN; fi++) {
        float r = rows[nl * (FIN + 1) + fi];
        float4 wv = Ws4[fi * 8 + fo4];
        acc.x += r * wv.x;
        acc.y += r * wv.y;
        acc.z += r * wv.z;
        acc.w += r * wv.w;
    }
    if (BIAS_RELU) {
        float4 bb = ((const float4*)scale_or_bias)[fo4];
        acc.x += bb.x; acc.y += bb.y; acc.z += bb.z; acc.w += bb.w;
        acc.x = acc.x > 0.f ? acc.x : 0.f;
        acc.y = acc.y > 0.f ? acc.y : 0.f;
        acc.z = acc.z > 0.f ? acc.z : 0.f;
        acc.w = acc.w > 0.f ? acc.w : 0.f;
    } else {
        float di = scale_or_bias[n];
        acc.x *= di; acc.y *= di; acc.z *= di; acc.w *= di;
    }
    ((float4*)h)[(size_t)n * 8 + fo4] = acc;
}

// ---- fc1 partials: part[b][g][j] = sum_{k in chunk b} h3[g][k]*w[k][j]; no atomics ----
__global__ void fc1_kernel(const float* __restrict__ h3, const float* __restrict__ w,
                           float* __restrict__ part) {
    __shared__ float hs[NUM_GRAPHS * FC1_KCHUNK];  // 8 KB
    int t = threadIdx.x;
    int kbase = blockIdx.x * FC1_KCHUNK;
    for (int i = t; i < NUM_GRAPHS * FC1_KCHUNK; i += 256) {
        int g = i >> 7;  // FC1_KCHUNK == 128
        int kk = i & 127;
        hs[i] = h3[(size_t)g * FC1_IN + kbase + kk];
    }
    __syncthreads();
    int kl = t & 3;
    int c = t >> 2;
    float4 acc[NUM_GRAPHS];
#pragma unroll
    for (int g = 0; g < NUM_GRAPHS; g++) acc[g] = make_float4(0.f, 0.f, 0.f, 0.f);
    const float4* w4 = (const float4*)w;  // row k = 64 float4
    for (int i0 = 0; i0 < FC1_KCHUNK / 4; i0 += 4) {
        float4 wv[4];
#pragma unroll
        for (int u = 0; u < 4; u++)
            wv[u] = w4[(size_t)(kbase + kl + 4 * (i0 + u)) * (FC1_OUT / 4) + c];
#pragma unroll
        for (int u = 0; u < 4; u++) {
            int kk = kl + 4 * (i0 + u);
#pragma unroll
            for (int g = 0; g < NUM_GRAPHS; g++) {
                float hg = hs[g * FC1_KCHUNK + kk];
                acc[g].x += hg * wv[u].x;
                acc[g].y += hg * wv[u].y;
                acc[g].z += hg * wv[u].z;
                acc[g].w += hg * wv[u].w;
            }
        }
    }
#pragma unroll
    for (int g = 0; g < NUM_GRAPHS; g++) {
        acc[g].x += __shfl_xor(acc[g].x, 1);
        acc[g].y += __shfl_xor(acc[g].y, 1);
        acc[g].z += __shfl_xor(acc[g].z, 1);
        acc[g].w += __shfl_xor(acc[g].w, 1);
        acc[g].x += __shfl_xor(acc[g].x, 2);
        acc[g].y += __shfl_xor(acc[g].y, 2);
        acc[g].z += __shfl_xor(acc[g].z, 2);
        acc[g].w += __shfl_xor(acc[g].w, 2);
    }
    if (kl == 0) {
        float4* p4 = (float4*)part;
#pragma unroll
        for (int g = 0; g < NUM_GRAPHS; g++)
            p4[(size_t)blockIdx.x * (NUM_GRAPHS * FC1_OUT / 4) + g * (FC1_OUT / 4) + c] = acc[g];
    }
}

// ---- reduce partials: out1[j'] += sum over 1024 blocks ----
__global__ void reduce_kernel(const float* __restrict__ part, float* __restrict__ out1) {
    int tid = blockIdx.x * 256 + threadIdx.x;  // 32768 threads
    int j = tid & 4095;
    int bq = tid >> 12;  // 0..7
    float s = 0.f;
#pragma unroll 8
    for (int u = 0; u < FC1_BLOCKS / 8; u++)
        s += part[(size_t)(bq * (FC1_BLOCKS / 8) + u) * (NUM_GRAPHS * FC1_OUT) + j];
    atomicAdd(&out1[j], s);
}

// ---- fc2 ----
__global__ void fc2_kernel(const float* __restrict__ out1, const float* __restrict__ fc1_b,
                           const float* __restrict__ w2, const float* __restrict__ b2,
                           float* __restrict__ out) {
    int g = blockIdx.x;
    int j = threadIdx.x;  // 0..63
    __shared__ float vs[FC1_OUT];
    for (int k = threadIdx.x; k < FC1_OUT; k += 64) {
        float v = out1[g * FC1_OUT + k] + fc1_b[k];
        vs[k] = v > 0.f ? v : 0.f;
    }
    __syncthreads();
    float acc = b2[j];
    for (int k = 0; k < FC1_OUT; k++) acc += vs[k] * w2[k * FC2_OUT + j];
    out[g * FC2_OUT + j] = acc;
}

extern "C" void kernel_launch(void* const* d_in, const int* in_sizes, int n_in,
                              void* d_out, int out_size, void* d_ws, size_t ws_size,
                              hipStream_t stream) {
    const float* x = (const float*)d_in[0];
    const int* ei = (const int*)d_in[1];
    const int* src = ei;
    const int* dst = ei + NUM_EDGES;
    const float* W1 = (const float*)d_in[2];
    const float* b1 = (const float*)d_in[3];
    const float* W2 = (const float*)d_in[4];
    const float* b2 = (const float*)d_in[5];
    const float* W3 = (const float*)d_in[6];
    const float* b3 = (const float*)d_in[7];
    const float* fc1_w = (const float*)d_in[8];
    const float* fc1_b = (const float*)d_in[9];
    const float* fc2_w = (const float*)d_in[10];
    const float* fc2_b = (const float*)d_in[11];
    float* out = (float*)d_out;

    // workspace layout (re-poisoned 0xAA each call; zero what we RMW)
    int* bucket_cursor = (int*)d_ws;                  // 256
    int* binned = bucket_cursor + 256;                // NB*BUCKET_CAP
    int* csr_src = binned + NB * BUCKET_CAP;          // NB*BUCKET_CAP (bucketed, gaps ok)
    int* rowstart = csr_src + NB * BUCKET_CAP;        // 65536
    int* rowend = rowstart + N_NODES;                 // 65536
    float* dinv = (float*)(rowend + N_NODES);         // 65536
    float* h_mm = dinv + N_NODES;                     // N*32 (layer1: xs | agg overlay)
    float* h_out = h_mm + (size_t)N_NODES * HIDDEN;   // N*32
    float* out1 = h_out + (size_t)N_NODES * HIDDEN;   // 16*256
    float* part = out1 + NUM_GRAPHS * FC1_OUT;        // 1024*4096
    float* xs = h_mm;                                 // N*16 (dead once layer1 matmul runs)
    float* agg = h_mm + (size_t)N_NODES * IN_FEAT;    // N*16

    initcur_kernel<<<1, 256, 0, stream>>>(bucket_cursor);
    binA_kernel<<<NUM_EDGES / EPB_A, 256, 0, stream>>>(src, dst, bucket_cursor, binned);
    sortB_kernel<<<NB, 256, 0, stream>>>(bucket_cursor, binned, csr_src, rowstart, rowend, dinv, x, xs);

    // layer 1: aggregate 16-feat x~, then matmul + bias + relu
    gather_kernel<4, 2, false><<<N_NODES * 4 / 256, 256, 0, stream>>>(
        rowstart, rowend, csr_src, xs, dinv, nullptr, agg);
    matmul_kernel<IN_FEAT, true><<<N_NODES / 32, 256, 0, stream>>>(agg, W1, b1, h_out);

    // layers 2,3: matmul (*dinv) then gather (+bias, relu)
    const float* Wl[2] = {W2, W3};
    const float* bl[2] = {b2, b3};
    for (int l = 0; l < 2; l++) {
        matmul_kernel<HIDDEN, false><<<N_NODES / 32, 256, 0, stream>>>(h_out, Wl[l], dinv, h_mm);
        gather_kernel<8, 3, true><<<N_NODES * 8 / 256, 256, 0, stream>>>(
            rowstart, rowend, csr_src, h_mm, dinv, bl[l], h_out);
    }

    fc1_kernel<<<FC1_BLOCKS, 256, 0, stream>>>(h_out, fc1_w, part);
    hipMemsetAsync(out1, 0, NUM_GRAPHS * FC1_OUT * sizeof(float), stream);
    reduce_kernel<<<128, 256, 0, stream>>>(part, out1);
    fc2_kernel<<<NUM_GRAPHS, 64, 0, stream>>>(out1, fc1_b, fc2_w, fc2_b, out);
}

// Round 6
// 329.402 us; speedup vs baseline: 1.0803x; 1.0803x over previous
//
#include <hip/hip_runtime.h>

#define N_NODES 65536
#define IN_FEAT 16
#define HIDDEN 32
#define NUM_EDGES 1048576
#define NUM_GRAPHS 16
#define NODES_PER_GRAPH 4096
#define FC1_IN (NODES_PER_GRAPH * HIDDEN) /* 131072 */
#define FC1_OUT 256
#define FC2_OUT 64
#define FC1_KCHUNK 128
#define FC1_BLOCKS (FC1_IN / FC1_KCHUNK) /* 1024 */
#define NB 256          /* buckets = dst>>8 */
#define BUCKET_CAP 5120 /* mean 4096, sd 64 -> 16 sigma headroom */
#define EPB_A 4096      /* edges per phase-A block */

typedef _Float16 half8 __attribute__((ext_vector_type(8)));  // 16 B
typedef _Float16 half4v __attribute__((ext_vector_type(4))); // 8 B

// ---- init bucket cursors to fixed-capacity bases ----
__global__ void initcur_kernel(int* __restrict__ bucket_cursor) {
    bucket_cursor[threadIdx.x] = threadIdx.x * BUCKET_CAP;
}

// ---- phase A: bin edges by dst>>8 with chunk-contiguous writes ----
__global__ void binA_kernel(const int* __restrict__ src, const int* __restrict__ dst,
                            int* __restrict__ bucket_cursor, int* __restrict__ binned) {
    __shared__ int hist[NB];
    __shared__ int base[NB];
    __shared__ int cur[NB];
    int t = threadIdx.x;
    hist[t] = 0;
    __syncthreads();
    int e0 = blockIdx.x * EPB_A;
    int s[16], d[16];
#pragma unroll
    for (int i = 0; i < 16; i++) {
        int e = e0 + t + 256 * i;
        s[i] = src[e];
        d[i] = dst[e];
    }
#pragma unroll
    for (int i = 0; i < 16; i++) atomicAdd(&hist[d[i] >> 8], 1);
    __syncthreads();
    base[t] = atomicAdd(&bucket_cursor[t], hist[t]);
    cur[t] = 0;
    __syncthreads();
#pragma unroll
    for (int i = 0; i < 16; i++) {
        int b = d[i] >> 8;
        int r = atomicAdd(&cur[b], 1);
        binned[base[b] + r] = s[i] | ((d[i] & 255) << 16);
    }
}

// ---- phase B: per-bucket LDS counting sort by dst low byte ----
// emits csr (ushort), rowstart/rowend, dinv, and p0 = x*dinv in fp16.
__global__ void sortB_kernel(const int* __restrict__ bucket_cursor, const int* __restrict__ binned,
                             unsigned short* __restrict__ csr, int* __restrict__ rowstart,
                             int* __restrict__ rowend, float* __restrict__ dinv,
                             const float* __restrict__ x, half8* __restrict__ p0) {
    __shared__ int hist[NB];
    __shared__ int scanbuf[NB];
    __shared__ int start[NB];
    __shared__ int cur[NB];
    int t = threadIdx.x;
    int b = blockIdx.x;
    int bbase = b * BUCKET_CAP;
    int cnt = bucket_cursor[b] - bbase;
    hist[t] = 0;
    __syncthreads();
    for (int i = t; i < cnt; i += 256) atomicAdd(&hist[binned[bbase + i] >> 16], 1);
    __syncthreads();
    int v = hist[t];
    scanbuf[t] = v;
    __syncthreads();
    for (int off = 1; off < 256; off <<= 1) {
        int y = (t >= off) ? scanbuf[t - off] : 0;
        __syncthreads();
        scanbuf[t] += y;
        __syncthreads();
    }
    int excl = scanbuf[t] - v;  // exclusive prefix within bucket
    start[t] = excl;
    cur[t] = 0;
    __syncthreads();
    for (int i = t; i < cnt; i += 256) {
        int p = binned[bbase + i];
        int dl = p >> 16;
        int r = atomicAdd(&cur[dl], 1);
        csr[bbase + start[dl] + r] = (unsigned short)(p & 0xFFFF);
    }
    int n = b * 256 + t;
    rowstart[n] = bbase + excl;
    rowend[n] = bbase + excl + v;
    float di = rsqrtf((float)v + 1.0f);
    dinv[n] = di;
    const float4* x4 = (const float4*)x;
#pragma unroll
    for (int q = 0; q < 2; q++) {
        float4 a = x4[(size_t)n * 4 + 2 * q];
        float4 c = x4[(size_t)n * 4 + 2 * q + 1];
        half8 hh;
        hh[0] = (_Float16)(a.x * di); hh[1] = (_Float16)(a.y * di);
        hh[2] = (_Float16)(a.z * di); hh[3] = (_Float16)(a.w * di);
        hh[4] = (_Float16)(c.x * di); hh[5] = (_Float16)(c.y * di);
        hh[6] = (_Float16)(c.z * di); hh[7] = (_Float16)(c.w * di);
        p0[(size_t)n * 2 + q] = hh;
    }
}

// ---- gather: q[n] = sum_{s in N(n)} p[s] + p[n]; pure fp32 sum of fp16 rows ----
// F8 = half8-chunks per row (2 -> 16 feats, 4 -> 32 feats). F8 lanes per node.
template <int F8, int LOG2F8>
__global__ void gather_kernel(const int* __restrict__ rowstart, const int* __restrict__ rowend,
                              const unsigned short* __restrict__ csr,
                              const half8* __restrict__ p, float* __restrict__ q) {
    int t = blockIdx.x * 256 + threadIdx.x;
    int f8 = t & (F8 - 1);
    int n = t >> LOG2F8;
    half8 self = p[(size_t)n * F8 + f8];
    float acc[8];
#pragma unroll
    for (int e = 0; e < 8; e++) acc[e] = (float)self[e];
    int beg = rowstart[n];
    int end = rowend[n];
    int i = beg;
    for (; i + 8 <= end; i += 8) {
        int s[8];
#pragma unroll
        for (int u = 0; u < 8; u++) s[u] = csr[i + u];
        half8 a[8];
#pragma unroll
        for (int u = 0; u < 8; u++) a[u] = p[(size_t)s[u] * F8 + f8];
#pragma unroll
        for (int u = 0; u < 8; u++)
#pragma unroll
            for (int e = 0; e < 8; e++) acc[e] += (float)a[u][e];
    }
    if (i + 4 <= end) {
        int s[4];
#pragma unroll
        for (int u = 0; u < 4; u++) s[u] = csr[i + u];
        half8 a[4];
#pragma unroll
        for (int u = 0; u < 4; u++) a[u] = p[(size_t)s[u] * F8 + f8];
#pragma unroll
        for (int u = 0; u < 4; u++)
#pragma unroll
            for (int e = 0; e < 8; e++) acc[e] += (float)a[u][e];
        i += 4;
    }
    for (; i < end; i++) {
        half8 a = p[(size_t)csr[i] * F8 + f8];
#pragma unroll
        for (int e = 0; e < 8; e++) acc[e] += (float)a[e];
    }
    float4 lo = make_float4(acc[0], acc[1], acc[2], acc[3]);
    float4 hi = make_float4(acc[4], acc[5], acc[6], acc[7]);
    float4* q4 = (float4*)q;
    q4[((size_t)n * F8 + f8) * 2] = lo;
    q4[((size_t)n * F8 + f8) * 2 + 1] = hi;
}

// ---- matmul: v = relu(dinv[n]*(q[n]@W) + b); LAST: store fp32 h3, else p=v*dinv fp16 ----
template <int FIN, bool LAST>
__global__ void matmul_kernel(const float* __restrict__ q, const float* __restrict__ W,
                              const float* __restrict__ bias, const float* __restrict__ dinv,
                              void* __restrict__ outp) {
    __shared__ float4 Ws4[FIN * 8];           // W[FIN][32] as float4
    __shared__ float rows[32 * (FIN + 1)];    // +1 pad: conflict-free nl stride
    int t = threadIdx.x;
    for (int i = t; i < FIN * 8; i += 256) Ws4[i] = ((const float4*)W)[i];
    size_t base = (size_t)blockIdx.x * 32 * FIN;
    for (int i = t; i < 32 * FIN; i += 256) {
        int nn = i / FIN;
        int ff = i & (FIN - 1);
        rows[nn * (FIN + 1) + ff] = q[base + i];
    }
    __syncthreads();
    int fo4 = t & 7;
    int nl = t >> 3;
    int n = blockIdx.x * 32 + nl;
    float4 acc = make_float4(0.f, 0.f, 0.f, 0.f);
#pragma unroll
    for (int fi = 0; fi < FIN; fi++) {
        float r = rows[nl * (FIN + 1) + fi];
        float4 wv = Ws4[fi * 8 + fo4];
        acc.x += r * wv.x;
        acc.y += r * wv.y;
        acc.z += r * wv.z;
        acc.w += r * wv.w;
    }
    float di = dinv[n];
    float4 bb = ((const float4*)bias)[fo4];
    float4 v;
    v.x = acc.x * di + bb.x;
    v.y = acc.y * di + bb.y;
    v.z = acc.z * di + bb.z;
    v.w = acc.w * di + bb.w;
    v.x = v.x > 0.f ? v.x : 0.f;
    v.y = v.y > 0.f ? v.y : 0.f;
    v.z = v.z > 0.f ? v.z : 0.f;
    v.w = v.w > 0.f ? v.w : 0.f;
    if (LAST) {
        ((float4*)outp)[(size_t)n * 8 + fo4] = v;
    } else {
        half4v hv;
        hv[0] = (_Float16)(v.x * di);
        hv[1] = (_Float16)(v.y * di);
        hv[2] = (_Float16)(v.z * di);
        hv[3] = (_Float16)(v.w * di);
        ((half4v*)outp)[(size_t)n * 8 + fo4] = hv;
    }
}

// ---- fc1 partials: part[b][g][j] = sum_{k in chunk b} h3[g][k]*w[k][j]; no atomics ----
__global__ void fc1_kernel(const float* __restrict__ h3, const float* __restrict__ w,
                           float* __restrict__ part) {
    __shared__ float hs[NUM_GRAPHS * FC1_KCHUNK];  // 8 KB
    int t = threadIdx.x;
    int kbase = blockIdx.x * FC1_KCHUNK;
    for (int i = t; i < NUM_GRAPHS * FC1_KCHUNK; i += 256) {
        int g = i >> 7;  // FC1_KCHUNK == 128
        int kk = i & 127;
        hs[i] = h3[(size_t)g * FC1_IN + kbase + kk];
    }
    __syncthreads();
    int kl = t & 3;
    int c = t >> 2;
    float4 acc[NUM_GRAPHS];
#pragma unroll
    for (int g = 0; g < NUM_GRAPHS; g++) acc[g] = make_float4(0.f, 0.f, 0.f, 0.f);
    const float4* w4 = (const float4*)w;  // row k = 64 float4
    for (int i0 = 0; i0 < FC1_KCHUNK / 4; i0 += 4) {
        float4 wv[4];
#pragma unroll
        for (int u = 0; u < 4; u++)
            wv[u] = w4[(size_t)(kbase + kl + 4 * (i0 + u)) * (FC1_OUT / 4) + c];
#pragma unroll
        for (int u = 0; u < 4; u++) {
            int kk = kl + 4 * (i0 + u);
#pragma unroll
            for (int g = 0; g < NUM_GRAPHS; g++) {
                float hg = hs[g * FC1_KCHUNK + kk];
                acc[g].x += hg * wv[u].x;
                acc[g].y += hg * wv[u].y;
                acc[g].z += hg * wv[u].z;
                acc[g].w += hg * wv[u].w;
            }
        }
    }
#pragma unroll
    for (int g = 0; g < NUM_GRAPHS; g++) {
        acc[g].x += __shfl_xor(acc[g].x, 1);
        acc[g].y += __shfl_xor(acc[g].y, 1);
        acc[g].z += __shfl_xor(acc[g].z, 1);
        acc[g].w += __shfl_xor(acc[g].w, 1);
        acc[g].x += __shfl_xor(acc[g].x, 2);
        acc[g].y += __shfl_xor(acc[g].y, 2);
        acc[g].z += __shfl_xor(acc[g].z, 2);
        acc[g].w += __shfl_xor(acc[g].w, 2);
    }
    if (kl == 0) {
        float4* p4 = (float4*)part;
#pragma unroll
        for (int g = 0; g < NUM_GRAPHS; g++)
            p4[(size_t)blockIdx.x * (NUM_GRAPHS * FC1_OUT / 4) + g * (FC1_OUT / 4) + c] = acc[g];
    }
}

// ---- reduce partials: out1[j'] += sum over 1024 blocks ----
__global__ void reduce_kernel(const float* __restrict__ part, float* __restrict__ out1) {
    int tid = blockIdx.x * 256 + threadIdx.x;  // 32768 threads
    int j = tid & 4095;
    int bq = tid >> 12;  // 0..7
    float s = 0.f;
#pragma unroll 8
    for (int u = 0; u < FC1_BLOCKS / 8; u++)
        s += part[(size_t)(bq * (FC1_BLOCKS / 8) + u) * (NUM_GRAPHS * FC1_OUT) + j];
    atomicAdd(&out1[j], s);
}

// ---- fc2 ----
__global__ void fc2_kernel(const float* __restrict__ out1, const float* __restrict__ fc1_b,
                           const float* __restrict__ w2, const float* __restrict__ b2,
                           float* __restrict__ out) {
    int g = blockIdx.x;
    int j = threadIdx.x;  // 0..63
    __shared__ float vs[FC1_OUT];
    for (int k = threadIdx.x; k < FC1_OUT; k += 64) {
        float v = out1[g * FC1_OUT + k] + fc1_b[k];
        vs[k] = v > 0.f ? v : 0.f;
    }
    __syncthreads();
    float acc = b2[j];
    for (int k = 0; k < FC1_OUT; k++) acc += vs[k] * w2[k * FC2_OUT + j];
    out[g * FC2_OUT + j] = acc;
}

extern "C" void kernel_launch(void* const* d_in, const int* in_sizes, int n_in,
                              void* d_out, int out_size, void* d_ws, size_t ws_size,
                              hipStream_t stream) {
    const float* x = (const float*)d_in[0];
    const int* ei = (const int*)d_in[1];
    const int* src = ei;
    const int* dst = ei + NUM_EDGES;
    const float* W1 = (const float*)d_in[2];
    const float* b1 = (const float*)d_in[3];
    const float* W2 = (const float*)d_in[4];
    const float* b2 = (const float*)d_in[5];
    const float* W3 = (const float*)d_in[6];
    const float* b3 = (const float*)d_in[7];
    const float* fc1_w = (const float*)d_in[8];
    const float* fc1_b = (const float*)d_in[9];
    const float* fc2_w = (const float*)d_in[10];
    const float* fc2_b = (const float*)d_in[11];
    float* out = (float*)d_out;

    // workspace layout (re-poisoned 0xAA each call; zero what we RMW)
    int* bucket_cursor = (int*)d_ws;                       // 1 KB
    int* binned = bucket_cursor + 256;                     // 5.24 MB
    unsigned short* csr = (unsigned short*)(binned + NB * BUCKET_CAP);  // 2.62 MB
    int* rowstart = (int*)(csr + NB * BUCKET_CAP);         // 256 KB
    int* rowend = rowstart + N_NODES;                      // 256 KB
    float* dinv = (float*)(rowend + N_NODES);              // 256 KB
    half8* p0 = (half8*)(dinv + N_NODES);                  // N*16 fp16 = 2 MB
    float* q0 = (float*)(p0 + (size_t)N_NODES * 2);        // N*16 f32 = 4 MB
    half8* p = (half8*)(q0 + (size_t)N_NODES * IN_FEAT);   // N*32 fp16 = 4 MB
    float* q = (float*)(p + (size_t)N_NODES * 4);          // N*32 f32 = 8 MB
    float* h3 = q + (size_t)N_NODES * HIDDEN;              // N*32 f32 = 8 MB
    float* out1 = h3 + (size_t)N_NODES * HIDDEN;           // 16 KB
    float* part = out1 + NUM_GRAPHS * FC1_OUT;             // 16 MB

    initcur_kernel<<<1, 256, 0, stream>>>(bucket_cursor);
    binA_kernel<<<NUM_EDGES / EPB_A, 256, 0, stream>>>(src, dst, bucket_cursor, binned);
    sortB_kernel<<<NB, 256, 0, stream>>>(bucket_cursor, binned, csr, rowstart, rowend, dinv, x, p0);

    // layer 1: gather p0 (16 feats) -> q0, matmul W1 -> p (fp16, 32 feats)
    gather_kernel<2, 1><<<N_NODES * 2 / 256, 256, 0, stream>>>(rowstart, rowend, csr, p0, q0);
    matmul_kernel<IN_FEAT, false><<<N_NODES / 32, 256, 0, stream>>>(q0, W1, b1, dinv, p);

    // layer 2: gather p -> q, matmul W2 -> p
    gather_kernel<4, 2><<<N_NODES * 4 / 256, 256, 0, stream>>>(rowstart, rowend, csr, p, q);
    matmul_kernel<HIDDEN, false><<<N_NODES / 32, 256, 0, stream>>>(q, W2, b2, dinv, p);

    // layer 3: gather p -> q, matmul W3 -> h3 (fp32)
    gather_kernel<4, 2><<<N_NODES * 4 / 256, 256, 0, stream>>>(rowstart, rowend, csr, p, q);
    matmul_kernel<HIDDEN, true><<<N_NODES / 32, 256, 0, stream>>>(q, W3, b3, dinv, h3);

    fc1_kernel<<<FC1_BLOCKS, 256, 0, stream>>>(h3, fc1_w, part);
    hipMemsetAsync(out1, 0, NUM_GRAPHS * FC1_OUT * sizeof(float), stream);
    reduce_kernel<<<128, 256, 0, stream>>>(part, out1);
    fc2_kernel<<<NUM_GRAPHS, 64, 0, stream>>>(out1, fc1_b, fc2_w, fc2_b, out);
}